// Round 1
// baseline (766.751 us; speedup 1.0000x reference)
//
#include <hip/hip_runtime.h>

#define NN 100000
#define EE 1600000
#define DIN 128
#define DH 64
#define DOUT 32

// ---------------- utility ----------------
__global__ void zero_kernel(float* __restrict__ p, int n) {
    int i = blockIdx.x * 256 + threadIdx.x;
    if (i < n) p[i] = 0.0f;
}

// count in-degree by dst
__global__ void deg_kernel(const int* __restrict__ dst, int* __restrict__ degi) {
    int e = blockIdx.x * 256 + threadIdx.x;
    if (e < EE) atomicAdd(&degi[dst[e]], 1);
}

// dinv = 1/sqrt(deg+1), inv = 1/(deg+1)
__global__ void norm_kernel(const int* __restrict__ degi,
                            float* __restrict__ dinv, float* __restrict__ inv) {
    int i = blockIdx.x * 256 + threadIdx.x;
    if (i < NN) {
        float d = (float)degi[i] + 1.0f;
        dinv[i] = 1.0f / sqrtf(d);
        inv[i]  = 1.0f / d;
    }
}

// ---------------- GEMM: Y[n,NC] = X[n,K] @ W[K,NC] ----------------
// block = 256 threads; each thread computes 1 row x 4 cols.
template <int K, int NC>
__global__ __launch_bounds__(256) void gemm_kernel(const float* __restrict__ X,
                                                   const float* __restrict__ W,
                                                   float* __restrict__ Y) {
    constexpr int CG   = NC / 4;    // col groups of 4
    constexpr int ROWS = 256 / CG;  // rows per block
    __shared__ float Wl[K * NC];
    __shared__ float Xl[ROWS * K];
    const int tid  = threadIdx.x;
    const int row0 = blockIdx.x * ROWS;

    for (int t = tid; t < K * NC; t += 256) Wl[t] = W[t];
    for (int t = tid; t < ROWS * K; t += 256) Xl[t] = X[row0 * K + t];
    __syncthreads();

    const int cg = tid % CG;
    const int rs = tid / CG;
    const float* xr = &Xl[rs * K];
    float a0 = 0.f, a1 = 0.f, a2 = 0.f, a3 = 0.f;
#pragma unroll
    for (int k = 0; k < K; k += 4) {
        float4 xv = *(const float4*)&xr[k];
        float4 w0 = *(const float4*)&Wl[(k + 0) * NC + cg * 4];
        float4 w1 = *(const float4*)&Wl[(k + 1) * NC + cg * 4];
        float4 w2 = *(const float4*)&Wl[(k + 2) * NC + cg * 4];
        float4 w3 = *(const float4*)&Wl[(k + 3) * NC + cg * 4];
        a0 += xv.x * w0.x + xv.y * w1.x + xv.z * w2.x + xv.w * w3.x;
        a1 += xv.x * w0.y + xv.y * w1.y + xv.z * w2.y + xv.w * w3.y;
        a2 += xv.x * w0.z + xv.y * w1.z + xv.z * w2.z + xv.w * w3.z;
        a3 += xv.x * w0.w + xv.y * w1.w + xv.z * w2.w + xv.w * w3.w;
    }
    float4 r = make_float4(a0, a1, a2, a3);
    *(float4*)&Y[(row0 + rs) * NC + cg * 4] = r;
}

// ---------------- edge scatter: agg[dst] += H[src] * dinv[src]*dinv[dst] ----------------
template <int F, int LOGF>
__global__ __launch_bounds__(256) void scatter_kernel(const int* __restrict__ src,
                                                      const int* __restrict__ dst,
                                                      const float* __restrict__ dinv,
                                                      const float* __restrict__ H,
                                                      float* __restrict__ agg) {
    int gid = blockIdx.x * 256 + threadIdx.x;
    int e = gid >> LOGF;
    int j = gid & (F - 1);
    if (e < EE) {
        int s = src[e];
        int d = dst[e];
        float c = dinv[s] * dinv[d];
        atomicAdd(&agg[d * F + j], H[s * F + j] * c);
    }
}

// ---------------- finish layer 1: h1 = relu(agg + H*inv[i] + b[j]) (in place on agg) ----
template <int F, int LOGF>
__global__ void finish_kernel(float* __restrict__ agg, const float* __restrict__ H,
                              const float* __restrict__ inv, const float* __restrict__ b) {
    int gid = blockIdx.x * 256 + threadIdx.x;
    if (gid < NN * F) {
        int i = gid >> LOGF;
        int j = gid & (F - 1);
        float v = agg[gid] + H[gid] * inv[i] + b[j];
        agg[gid] = fmaxf(v, 0.0f);
    }
}

// ---------------- finish layer 2 + fc: h2 in place on agg2 (=d_out+NN), scores ----------
__global__ void finish2_kernel(float* __restrict__ agg, const float* __restrict__ H,
                               const float* __restrict__ inv, const float* __restrict__ b,
                               const float* __restrict__ fcw, const float* __restrict__ fcb,
                               float* __restrict__ scores) {
    int gid = blockIdx.x * 256 + threadIdx.x;
    int i = gid >> 5;
    int j = gid & 31;
    float v = 0.0f;
    if (gid < NN * 32) {
        v = agg[gid] + H[gid] * inv[i] + b[j];
        v = fmaxf(v, 0.0f);
        agg[gid] = v;          // h output (in place)
        v *= fcw[j];
    }
#pragma unroll
    for (int m = 16; m >= 1; m >>= 1) v += __shfl_xor(v, m, 32);
    if (j == 0 && gid < NN * 32) scores[i] = v + fcb[0];
}

extern "C" void kernel_launch(void* const* d_in, const int* in_sizes, int n_in,
                              void* d_out, int out_size, void* d_ws, size_t ws_size,
                              hipStream_t stream) {
    const float* x   = (const float*)d_in[0];
    const int*   ei  = (const int*)d_in[1];
    const float* W1  = (const float*)d_in[2];
    const float* b1  = (const float*)d_in[3];
    const float* W2  = (const float*)d_in[4];
    const float* b2  = (const float*)d_in[5];
    const float* fcw = (const float*)d_in[6];
    const float* fcb = (const float*)d_in[7];
    const int* src = ei;
    const int* dst = ei + EE;

    float* ws   = (float*)d_ws;
    float* dinv = ws;                 // NN
    float* inv  = ws + NN;            // NN
    int*   degi = (int*)(ws + 2 * NN);// NN
    float* H1   = ws + 3 * NN;        // NN*64
    float* agg1 = H1 + NN * DH;       // NN*64 (becomes h1)
    float* H2   = agg1 + NN * DH;     // NN*32

    float* out    = (float*)d_out;
    float* scores = out;              // NN
    float* agg2   = out + NN;         // NN*32 (becomes h2 in place)

    const int T = 256;
    // 1. deg counts
    zero_kernel<<<(NN + T - 1) / T, T, 0, stream>>>((float*)degi, NN);
    deg_kernel<<<(EE + T - 1) / T, T, 0, stream>>>(dst, degi);
    norm_kernel<<<(NN + T - 1) / T, T, 0, stream>>>(degi, dinv, inv);
    // 2. layer 1
    gemm_kernel<DIN, DH><<<NN / (256 / (DH / 4)), T, 0, stream>>>(x, W1, H1);
    zero_kernel<<<(NN * DH + T - 1) / T, T, 0, stream>>>(agg1, NN * DH);
    scatter_kernel<DH, 6><<<(EE * DH + T - 1) / T, T, 0, stream>>>(src, dst, dinv, H1, agg1);
    finish_kernel<DH, 6><<<(NN * DH + T - 1) / T, T, 0, stream>>>(agg1, H1, inv, b1);
    // 3. layer 2
    gemm_kernel<DH, DOUT><<<NN / (256 / (DOUT / 4)), T, 0, stream>>>(agg1, W2, H2);
    zero_kernel<<<(NN * DOUT + T - 1) / T, T, 0, stream>>>(agg2, NN * DOUT);
    scatter_kernel<DOUT, 5><<<(EE * DOUT + T - 1) / T, T, 0, stream>>>(src, dst, dinv, H2, agg2);
    finish2_kernel<<<(NN * DOUT + T - 1) / T, T, 0, stream>>>(agg2, H2, inv, b2, fcw, fcb, scores);
}

// Round 2
// 543.794 us; speedup vs baseline: 1.4100x; 1.4100x over previous
//
#include <hip/hip_runtime.h>

#define NN 100000
#define EE 1600000
#define DIN 128
#define DH 64
#define DOUT 32
#define SB 1024            // elements per scan block
#define NB ((NN + SB - 1) / SB)   // 98 scan blocks

// ---------------- utility ----------------
__global__ void zero_int_kernel(int* __restrict__ p, int n) {
    int i = blockIdx.x * 256 + threadIdx.x;
    if (i < n) p[i] = 0;
}

// count in-degree by dst (int atomics, cheap)
__global__ void deg_kernel(const int* __restrict__ dst, int* __restrict__ degi) {
    int e = blockIdx.x * 256 + threadIdx.x;
    if (e < EE) atomicAdd(&degi[dst[e]], 1);
}

// dinv = 1/sqrt(deg+1)
__global__ void norm_kernel(const int* __restrict__ degi, float* __restrict__ dinv) {
    int i = blockIdx.x * 256 + threadIdx.x;
    if (i < NN) dinv[i] = 1.0f / sqrtf((float)degi[i] + 1.0f);
}

// ---------------- hierarchical exclusive scan over degi -> offsets ----------------
// scan1: per-block (1024 elems) sums
__global__ __launch_bounds__(256) void scan1_kernel(const int* __restrict__ degi,
                                                    int* __restrict__ partial) {
    __shared__ int sm[256];
    int t = threadIdx.x;
    int base = blockIdx.x * SB + t * 4;
    int s = 0;
#pragma unroll
    for (int k = 0; k < 4; k++) { int i = base + k; if (i < NN) s += degi[i]; }
    sm[t] = s; __syncthreads();
    for (int off = 128; off > 0; off >>= 1) {
        if (t < off) sm[t] += sm[t + off];
        __syncthreads();
    }
    if (t == 0) partial[blockIdx.x] = sm[0];
}

// scan2: single block scans NB partials -> partial_off (exclusive); writes offsets[NN]=total
__global__ __launch_bounds__(128) void scan2_kernel(const int* __restrict__ partial,
                                                    int* __restrict__ partial_off,
                                                    int* __restrict__ offsets) {
    __shared__ int sm[128];
    int t = threadIdx.x;
    int v = (t < NB) ? partial[t] : 0;
    sm[t] = v; __syncthreads();
    for (int off = 1; off < 128; off <<= 1) {
        int x = (t >= off) ? sm[t - off] : 0;
        __syncthreads();
        sm[t] += x;
        __syncthreads();
    }
    if (t < NB) partial_off[t] = sm[t] - v;   // exclusive
    if (t == 127) offsets[NN] = sm[127];       // total (=EE)
}

// scan3: per-block exclusive scan + block offset; writes offsets and cursor (cursor may alias degi)
__global__ __launch_bounds__(256) void scan3_kernel(const int* __restrict__ degi,
                                                    const int* __restrict__ partial_off,
                                                    int* __restrict__ offsets,
                                                    int* __restrict__ cursor) {
    __shared__ int sm[256];
    int t = threadIdx.x;
    int base = blockIdx.x * SB + t * 4;
    int v[4]; int s = 0;
#pragma unroll
    for (int k = 0; k < 4; k++) { int i = base + k; v[k] = (i < NN) ? degi[i] : 0; s += v[k]; }
    sm[t] = s; __syncthreads();
    for (int off = 1; off < 256; off <<= 1) {
        int x = (t >= off) ? sm[t - off] : 0;
        __syncthreads();
        sm[t] += x;
        __syncthreads();
    }
    int run = partial_off[blockIdx.x] + sm[t] - s;  // exclusive prefix for this thread's chunk
#pragma unroll
    for (int k = 0; k < 4; k++) {
        int i = base + k;
        if (i < NN) { offsets[i] = run; cursor[i] = run; }
        run += v[k];
    }
}

// fill CSR: csr[pos] = src, bucketed by dst
__global__ void fill_kernel(const int* __restrict__ src, const int* __restrict__ dst,
                            int* __restrict__ cursor, int* __restrict__ csr) {
    int e = blockIdx.x * 256 + threadIdx.x;
    if (e < EE) {
        int pos = atomicAdd(&cursor[dst[e]], 1);
        csr[pos] = src[e];
    }
}

// ---------------- GEMM: Y[n,NC] = X[n,K] @ W[K,NC] ----------------
template <int K, int NC>
__global__ __launch_bounds__(256) void gemm_kernel(const float* __restrict__ X,
                                                   const float* __restrict__ W,
                                                   float* __restrict__ Y) {
    constexpr int CG   = NC / 4;
    constexpr int ROWS = 256 / CG;
    __shared__ float Wl[K * NC];
    __shared__ float Xl[ROWS * K];
    const int tid  = threadIdx.x;
    const int row0 = blockIdx.x * ROWS;

    for (int t = tid; t < K * NC; t += 256) Wl[t] = W[t];
    for (int t = tid; t < ROWS * K; t += 256) Xl[t] = X[row0 * K + t];
    __syncthreads();

    const int cg = tid % CG;
    const int rs = tid / CG;
    const float* xr = &Xl[rs * K];
    float a0 = 0.f, a1 = 0.f, a2 = 0.f, a3 = 0.f;
#pragma unroll
    for (int k = 0; k < K; k += 4) {
        float4 xv = *(const float4*)&xr[k];
        float4 w0 = *(const float4*)&Wl[(k + 0) * NC + cg * 4];
        float4 w1 = *(const float4*)&Wl[(k + 1) * NC + cg * 4];
        float4 w2 = *(const float4*)&Wl[(k + 2) * NC + cg * 4];
        float4 w3 = *(const float4*)&Wl[(k + 3) * NC + cg * 4];
        a0 += xv.x * w0.x + xv.y * w1.x + xv.z * w2.x + xv.w * w3.x;
        a1 += xv.x * w0.y + xv.y * w1.y + xv.z * w2.y + xv.w * w3.y;
        a2 += xv.x * w0.z + xv.y * w1.z + xv.z * w2.z + xv.w * w3.z;
        a3 += xv.x * w0.w + xv.y * w1.w + xv.z * w2.w + xv.w * w3.w;
    }
    *(float4*)&Y[(row0 + rs) * NC + cg * 4] = make_float4(a0, a1, a2, a3);
}

// ---------------- gather layer 1 (F=64): one wave per node, fused finish ----------------
__global__ __launch_bounds__(256) void gather1_kernel(const int* __restrict__ offsets,
                                                      const int* __restrict__ csr,
                                                      const float* __restrict__ dinv,
                                                      const float* __restrict__ H,
                                                      const float* __restrict__ b,
                                                      float* __restrict__ out) {
    int node = (blockIdx.x * 256 + threadIdx.x) >> 6;
    int lane = threadIdx.x & 63;
    if (node >= NN) return;
    int start = offsets[node], end = offsets[node + 1];
    float acc = 0.f;
    int k = start;
    for (; k + 1 < end; k += 2) {
        int s0 = csr[k], s1 = csr[k + 1];
        float h0 = H[s0 * DH + lane];
        float h1 = H[s1 * DH + lane];
        acc += h0 * dinv[s0] + h1 * dinv[s1];
    }
    if (k < end) { int s = csr[k]; acc += H[s * DH + lane] * dinv[s]; }
    float dv = dinv[node];
    float v = acc * dv + H[node * DH + lane] * (dv * dv) + b[lane];
    out[node * DH + lane] = fmaxf(v, 0.f);
}

// ---------------- gather layer 2 (F=32): wave per node, 2 edges/iter, fused fc ----------
__global__ __launch_bounds__(256) void gather2_kernel(const int* __restrict__ offsets,
                                                      const int* __restrict__ csr,
                                                      const float* __restrict__ dinv,
                                                      const float* __restrict__ H,
                                                      const float* __restrict__ b,
                                                      const float* __restrict__ fcw,
                                                      const float* __restrict__ fcb,
                                                      float* __restrict__ h2,
                                                      float* __restrict__ scores) {
    int node = (blockIdx.x * 256 + threadIdx.x) >> 6;
    int lane = threadIdx.x & 63;
    int j = lane & 31;
    int half = lane >> 5;
    if (node >= NN) return;
    int start = offsets[node], end = offsets[node + 1];
    float acc = 0.f;
    for (int k = start + half; k < end; k += 2) {
        int s = csr[k];
        acc += H[s * DOUT + j] * dinv[s];
    }
    acc += __shfl_xor(acc, 32);        // combine the two edge-halves
    float dv = dinv[node];
    float v = acc * dv + H[node * DOUT + j] * (dv * dv) + b[j];
    v = fmaxf(v, 0.f);
    if (lane < 32) h2[node * DOUT + j] = v;
    float sv = v * fcw[j];
#pragma unroll
    for (int m = 16; m >= 1; m >>= 1) sv += __shfl_xor(sv, m);
    if (lane == 0) scores[node] = sv + fcb[0];
}

extern "C" void kernel_launch(void* const* d_in, const int* in_sizes, int n_in,
                              void* d_out, int out_size, void* d_ws, size_t ws_size,
                              hipStream_t stream) {
    const float* x   = (const float*)d_in[0];
    const int*   ei  = (const int*)d_in[1];
    const float* W1  = (const float*)d_in[2];
    const float* b1  = (const float*)d_in[3];
    const float* W2  = (const float*)d_in[4];
    const float* b2  = (const float*)d_in[5];
    const float* fcw = (const float*)d_in[6];
    const float* fcb = (const float*)d_in[7];
    const int* src = ei;
    const int* dst = ei + EE;

    float* ws = (float*)d_ws;
    float* dinv        = ws;                                  // NN floats
    int*   degi        = (int*)(ws + NN);                     // NN ints (reused as cursor)
    int*   offsets     = (int*)(ws + 2 * NN);                 // NN+1 ints
    int*   partial     = (int*)(ws + 3 * NN + 64);            // NB ints
    int*   partial_off = (int*)(ws + 3 * NN + 256);           // NB ints
    int*   csr         = (int*)(ws + 3 * NN + 512);           // EE ints
    float* H1          = ws + 3 * NN + 512 + EE;              // NN*64
    float* h1          = H1 + NN * DH;                        // NN*64
    float* H2          = h1 + NN * DH;                        // NN*32

    float* out    = (float*)d_out;
    float* scores = out;          // NN
    float* h2     = out + NN;     // NN*32

    const int T = 256;
    // CSR build
    zero_int_kernel<<<(NN + T - 1) / T, T, 0, stream>>>(degi, NN);
    deg_kernel<<<(EE + T - 1) / T, T, 0, stream>>>(dst, degi);
    norm_kernel<<<(NN + T - 1) / T, T, 0, stream>>>(degi, dinv);
    scan1_kernel<<<NB, T, 0, stream>>>(degi, partial);
    scan2_kernel<<<1, 128, 0, stream>>>(partial, partial_off, offsets);
    scan3_kernel<<<NB, T, 0, stream>>>(degi, partial_off, offsets, degi /*cursor aliases degi*/);
    fill_kernel<<<(EE + T - 1) / T, T, 0, stream>>>(src, dst, degi, csr);
    // layer 1
    gemm_kernel<DIN, DH><<<NN / 16, T, 0, stream>>>(x, W1, H1);
    gather1_kernel<<<(NN * 64 + T - 1) / T, T, 0, stream>>>(offsets, csr, dinv, H1, b1, h1);
    // layer 2
    gemm_kernel<DH, DOUT><<<NN / 32, T, 0, stream>>>(h1, W2, H2);
    gather2_kernel<<<(NN * 64 + T - 1) / T, T, 0, stream>>>(offsets, csr, dinv, H2, b2, fcw, fcb, h2, scores);
}

// Round 4
// 397.613 us; speedup vs baseline: 1.9284x; 1.3676x over previous
//
#include <hip/hip_runtime.h>

#define NN 100000
#define EE 1600000
#define DIN 128
#define DH 64
#define DOUT 32

#define BSH 8                      // bucket = dst >> 8  (256 nodes/bucket)
#define BNODES 256
#define NBUCK ((NN + BNODES - 1) / BNODES)   // 391
#define CHUNK 4096                 // edges per Pass-A workgroup
#define NCHUNK ((EE + CHUNK - 1) / CHUNK)    // 391

// ---------------- zero bucket counters ----------------
__global__ void zero_bcnt_kernel(int* __restrict__ bcnt) {
    int i = blockIdx.x * 256 + threadIdx.x;   // FIX: was threadIdx.x only -> bcnt[256..390] unzeroed (0xAA poison) -> OOB writes
    if (i < NBUCK) bcnt[i] = 0;
}

// ---------------- bucket histogram (LDS-first) ----------------
__global__ __launch_bounds__(256) void bhist_kernel(const int* __restrict__ dst,
                                                    int* __restrict__ bcnt) {
    __shared__ int h[NBUCK];
    int t = threadIdx.x;
    for (int i = t; i < NBUCK; i += 256) h[i] = 0;
    __syncthreads();
    int base = blockIdx.x * CHUNK;
    int end = min(base + CHUNK, EE);
    for (int i = base + t; i < end; i += 256) atomicAdd(&h[dst[i] >> BSH], 1);
    __syncthreads();
    for (int i = t; i < NBUCK; i += 256) if (h[i]) atomicAdd(&bcnt[i], h[i]);
}

// ---------------- bucket exclusive scan (1 wg) ----------------
__global__ __launch_bounds__(256) void bscan_kernel(const int* __restrict__ bcnt,
                                                    int* __restrict__ bbase,
                                                    int* __restrict__ bcur,
                                                    int* __restrict__ offsets) {
    __shared__ int s2[256];
    int t = threadIdx.x;
    int a0 = (2 * t < NBUCK) ? bcnt[2 * t] : 0;
    int a1 = (2 * t + 1 < NBUCK) ? bcnt[2 * t + 1] : 0;
    s2[t] = a0 + a1;
    __syncthreads();
    for (int off = 1; off < 256; off <<= 1) {
        int x = (t >= off) ? s2[t - off] : 0;
        __syncthreads();
        s2[t] += x;
        __syncthreads();
    }
    int excl = s2[t] - a0 - a1;
    if (2 * t < NBUCK)     { bbase[2 * t] = excl;          bcur[2 * t] = excl; }
    if (2 * t + 1 < NBUCK) { bbase[2 * t + 1] = excl + a0; bcur[2 * t + 1] = excl + a0; }
    if (t == 255) { bbase[NBUCK] = s2[255]; offsets[NN] = s2[255]; }  // = EE
}

// ---------------- Pass A: bin edges into bucket-grouped tmp (packed (src<<8)|dstlow) ----
__global__ __launch_bounds__(256) void binA_kernel(const int* __restrict__ src,
                                                   const int* __restrict__ dst,
                                                   int* __restrict__ bcur,
                                                   unsigned* __restrict__ tmp) {
    __shared__ int hist[NBUCK];
    __shared__ int scn[NBUCK + 1];
    __shared__ int cur[NBUCK];
    __shared__ int gbase[NBUCK];
    __shared__ int s2[256];
    __shared__ unsigned staged[CHUNK];
    int t = threadIdx.x;
    for (int i = t; i < NBUCK; i += 256) hist[i] = 0;
    __syncthreads();
    int e0 = blockIdx.x * CHUNK;
    int nE = min(CHUNK, EE - e0);

    int my_e[16], my_bk[16];
#pragma unroll
    for (int k = 0; k < 16; k++) {
        int li = t + k * 256;
        bool ok = li < nE;
        int idx = ok ? (e0 + li) : e0;
        int d = dst[idx];
        int s = src[idx];
        int b = d >> BSH;
        my_e[k] = (s << 8) | (d & 255);
        my_bk[k] = ok ? b : -1;
        if (ok) atomicAdd(&hist[b], 1);
    }
    __syncthreads();
    // exclusive scan of hist -> scn/cur (2 entries per thread)
    int a0 = (2 * t < NBUCK) ? hist[2 * t] : 0;
    int a1 = (2 * t + 1 < NBUCK) ? hist[2 * t + 1] : 0;
    s2[t] = a0 + a1;
    __syncthreads();
    for (int off = 1; off < 256; off <<= 1) {
        int x = (t >= off) ? s2[t - off] : 0;
        __syncthreads();
        s2[t] += x;
        __syncthreads();
    }
    int excl = s2[t] - a0 - a1;
    if (2 * t < NBUCK)     { scn[2 * t] = excl;          cur[2 * t] = excl; }
    if (2 * t + 1 < NBUCK) { scn[2 * t + 1] = excl + a0; cur[2 * t + 1] = excl + a0; }
    if (t == 0) scn[NBUCK] = nE;
    __syncthreads();
    // reserve global space: one atomic per non-empty bucket
    for (int i = t; i < NBUCK; i += 256)
        gbase[i] = hist[i] ? atomicAdd(&bcur[i], hist[i]) : 0;
    __syncthreads();
    // stage bucket-grouped in LDS
#pragma unroll
    for (int k = 0; k < 16; k++) {
        if (my_bk[k] >= 0) {
            int lp = atomicAdd(&cur[my_bk[k]], 1);
            staged[lp] = (unsigned)my_e[k];
        }
    }
    __syncthreads();
    // coalesced write-out; find bucket by fixed-trip binary search over scn
    for (int i = t; i < nE; i += 256) {
        int lo = 0, hi = NBUCK;
#pragma unroll
        for (int step = 0; step < 9; step++) {
            int mid = (lo + hi) >> 1;
            bool c = scn[mid] <= i;
            lo = c ? mid : lo;
            hi = c ? hi : mid;
        }
        tmp[gbase[lo] + (i - scn[lo])] = staged[i];
    }
}

// ---------------- Pass B: per-bucket node histogram + scan -> offsets/dinv/csr ----------
__global__ __launch_bounds__(256) void binB_kernel(const unsigned* __restrict__ tmp,
                                                   const int* __restrict__ bbase,
                                                   int* __restrict__ csr,
                                                   int* __restrict__ offsets,
                                                   float* __restrict__ dinv) {
    __shared__ int hist[BNODES], cur[BNODES], sc[BNODES];
    int b = blockIdx.x, t = threadIdx.x;
    int e0 = bbase[b], e1 = bbase[b + 1];
    hist[t] = 0;
    __syncthreads();
    for (int i = e0 + t; i < e1; i += 256) atomicAdd(&hist[tmp[i] & 255], 1);
    __syncthreads();
    int v = hist[t];
    sc[t] = v;
    __syncthreads();
    for (int off = 1; off < 256; off <<= 1) {
        int x = (t >= off) ? sc[t - off] : 0;
        __syncthreads();
        sc[t] += x;
        __syncthreads();
    }
    int excl = sc[t] - v;
    cur[t] = e0 + excl;
    int node = (b << BSH) + t;
    if (node < NN) {
        offsets[node] = e0 + excl;
        dinv[node] = 1.0f / sqrtf((float)v + 1.0f);
    }
    __syncthreads();
    for (int i = e0 + t; i < e1; i += 256) {
        unsigned u = tmp[i];
        int pos = atomicAdd(&cur[u & 255], 1);
        csr[pos] = (int)(u >> 8);
    }
}

// ---------------- GEMM: Y[n,NC] = X[n,K] @ W[K,NC] ----------------
template <int K, int NC>
__global__ __launch_bounds__(256) void gemm_kernel(const float* __restrict__ X,
                                                   const float* __restrict__ W,
                                                   float* __restrict__ Y) {
    constexpr int CG   = NC / 4;
    constexpr int ROWS = 256 / CG;
    __shared__ float Wl[K * NC];
    __shared__ float Xl[ROWS * K];
    const int tid  = threadIdx.x;
    const int row0 = blockIdx.x * ROWS;

    for (int t = tid; t < K * NC; t += 256) Wl[t] = W[t];
    for (int t = tid; t < ROWS * K; t += 256) Xl[t] = X[row0 * K + t];
    __syncthreads();

    const int cg = tid % CG;
    const int rs = tid / CG;
    const float* xr = &Xl[rs * K];
    float a0 = 0.f, a1 = 0.f, a2 = 0.f, a3 = 0.f;
#pragma unroll
    for (int k = 0; k < K; k += 4) {
        float4 xv = *(const float4*)&xr[k];
        float4 w0 = *(const float4*)&Wl[(k + 0) * NC + cg * 4];
        float4 w1 = *(const float4*)&Wl[(k + 1) * NC + cg * 4];
        float4 w2 = *(const float4*)&Wl[(k + 2) * NC + cg * 4];
        float4 w3 = *(const float4*)&Wl[(k + 3) * NC + cg * 4];
        a0 += xv.x * w0.x + xv.y * w1.x + xv.z * w2.x + xv.w * w3.x;
        a1 += xv.x * w0.y + xv.y * w1.y + xv.z * w2.y + xv.w * w3.y;
        a2 += xv.x * w0.z + xv.y * w1.z + xv.z * w2.z + xv.w * w3.z;
        a3 += xv.x * w0.w + xv.y * w1.w + xv.z * w2.w + xv.w * w3.w;
    }
    *(float4*)&Y[(row0 + rs) * NC + cg * 4] = make_float4(a0, a1, a2, a3);
}

// ---------------- gather layer 1 (F=64): one wave per node, fused finish ----------------
__global__ __launch_bounds__(256) void gather1_kernel(const int* __restrict__ offsets,
                                                      const int* __restrict__ csr,
                                                      const float* __restrict__ dinv,
                                                      const float* __restrict__ H,
                                                      const float* __restrict__ b,
                                                      float* __restrict__ out) {
    int node = (blockIdx.x * 256 + threadIdx.x) >> 6;
    int lane = threadIdx.x & 63;
    if (node >= NN) return;
    int start = offsets[node], end = offsets[node + 1];
    float acc = 0.f;
    int k = start;
    for (; k + 1 < end; k += 2) {
        int s0 = csr[k], s1 = csr[k + 1];
        float h0 = H[s0 * DH + lane];
        float h1 = H[s1 * DH + lane];
        acc += h0 * dinv[s0] + h1 * dinv[s1];
    }
    if (k < end) { int s = csr[k]; acc += H[s * DH + lane] * dinv[s]; }
    float dv = dinv[node];
    float v = acc * dv + H[node * DH + lane] * (dv * dv) + b[lane];
    out[node * DH + lane] = fmaxf(v, 0.f);
}

// ---------------- gather layer 2 (F=32): wave per node, fused fc ----------
__global__ __launch_bounds__(256) void gather2_kernel(const int* __restrict__ offsets,
                                                      const int* __restrict__ csr,
                                                      const float* __restrict__ dinv,
                                                      const float* __restrict__ H,
                                                      const float* __restrict__ b,
                                                      const float* __restrict__ fcw,
                                                      const float* __restrict__ fcb,
                                                      float* __restrict__ h2,
                                                      float* __restrict__ scores) {
    int node = (blockIdx.x * 256 + threadIdx.x) >> 6;
    int lane = threadIdx.x & 63;
    int j = lane & 31;
    int half = lane >> 5;
    if (node >= NN) return;
    int start = offsets[node], end = offsets[node + 1];
    float acc = 0.f;
    for (int k = start + half; k < end; k += 2) {
        int s = csr[k];
        acc += H[s * DOUT + j] * dinv[s];
    }
    acc += __shfl_xor(acc, 32);
    float dv = dinv[node];
    float v = acc * dv + H[node * DOUT + j] * (dv * dv) + b[j];
    v = fmaxf(v, 0.f);
    if (lane < 32) h2[node * DOUT + j] = v;
    float sv = v * fcw[j];
#pragma unroll
    for (int m = 16; m >= 1; m >>= 1) sv += __shfl_xor(sv, m);
    if (lane == 0) scores[node] = sv + fcb[0];
}

extern "C" void kernel_launch(void* const* d_in, const int* in_sizes, int n_in,
                              void* d_out, int out_size, void* d_ws, size_t ws_size,
                              hipStream_t stream) {
    const float* x   = (const float*)d_in[0];
    const int*   ei  = (const int*)d_in[1];
    const float* W1  = (const float*)d_in[2];
    const float* b1  = (const float*)d_in[3];
    const float* W2  = (const float*)d_in[4];
    const float* b2  = (const float*)d_in[5];
    const float* fcw = (const float*)d_in[6];
    const float* fcb = (const float*)d_in[7];
    const int* src = ei;
    const int* dst = ei + EE;

    float* ws = (float*)d_ws;
    float* dinv    = ws;                          // NN
    int*   offsets = (int*)(ws + NN);             // NN+1
    int*   bcnt    = (int*)(ws + 2 * NN + 64);    // NBUCK
    int*   bbase   = bcnt + 512;                  // NBUCK+1
    int*   bcur    = bbase + 512;                 // NBUCK
    int*   csr     = bcur + 512;                  // EE
    float* bigreg  = (float*)(csr + EE);          // max(EE, NN*64): tmp then H1
    unsigned* tmp  = (unsigned*)bigreg;           // EE (dead after binB)
    float* H1      = bigreg;                      // NN*64 (after binB)
    float* h1      = bigreg + NN * DH;            // NN*64
    float* H2      = h1 + NN * DH;                // NN*32

    float* out    = (float*)d_out;
    float* scores = out;          // NN
    float* h2     = out + NN;     // NN*32

    const int T = 256;
    // CSR build (two-pass binning)
    zero_bcnt_kernel<<<2, 256, 0, stream>>>(bcnt);
    bhist_kernel<<<NCHUNK, T, 0, stream>>>(dst, bcnt);
    bscan_kernel<<<1, T, 0, stream>>>(bcnt, bbase, bcur, offsets);
    binA_kernel<<<NCHUNK, T, 0, stream>>>(src, dst, bcur, tmp);
    binB_kernel<<<NBUCK, T, 0, stream>>>(tmp, bbase, csr, offsets, dinv);
    // layer 1 (gemm1 after binB so H1 can reuse tmp's region)
    gemm_kernel<DIN, DH><<<NN / 16, T, 0, stream>>>(x, W1, H1);
    gather1_kernel<<<(NN * 64 + T - 1) / T, T, 0, stream>>>(offsets, csr, dinv, H1, b1, h1);
    // layer 2
    gemm_kernel<DH, DOUT><<<NN / 32, T, 0, stream>>>(h1, W2, H2);
    gather2_kernel<<<(NN * 64 + T - 1) / T, T, 0, stream>>>(offsets, csr, dinv, H2, b2, fcw, fcb, h2, scores);
}

// Round 5
// 313.224 us; speedup vs baseline: 2.4479x; 1.2694x over previous
//
#include <hip/hip_runtime.h>

#define NN 100000
#define EE 1600000
#define DIN 128
#define DH 64
#define DOUT 32

#define BSH 8                      // bucket = dst >> 8  (256 nodes/bucket)
#define BNODES 256
#define NBUCK ((NN + BNODES - 1) / BNODES)   // 391
#define CHUNK 4096                 // edges per Pass-A workgroup
#define NCHUNK ((EE + CHUNK - 1) / CHUNK)    // 391

// ---------------- zero bucket counters ----------------
__global__ void zero_bcnt_kernel(int* __restrict__ bcnt) {
    int i = blockIdx.x * 256 + threadIdx.x;
    if (i < NBUCK) bcnt[i] = 0;
}

// ---------------- bucket histogram (LDS-first) ----------------
__global__ __launch_bounds__(256) void bhist_kernel(const int* __restrict__ dst,
                                                    int* __restrict__ bcnt) {
    __shared__ int h[NBUCK];
    int t = threadIdx.x;
    for (int i = t; i < NBUCK; i += 256) h[i] = 0;
    __syncthreads();
    int base = blockIdx.x * CHUNK;
    int end = min(base + CHUNK, EE);
    for (int i = base + t; i < end; i += 256) atomicAdd(&h[dst[i] >> BSH], 1);
    __syncthreads();
    for (int i = t; i < NBUCK; i += 256) if (h[i]) atomicAdd(&bcnt[i], h[i]);
}

// ---------------- bucket exclusive scan (1 wg) ----------------
__global__ __launch_bounds__(256) void bscan_kernel(const int* __restrict__ bcnt,
                                                    int* __restrict__ bbase,
                                                    int* __restrict__ bcur,
                                                    int* __restrict__ offsets) {
    __shared__ int s2[256];
    int t = threadIdx.x;
    int a0 = (2 * t < NBUCK) ? bcnt[2 * t] : 0;
    int a1 = (2 * t + 1 < NBUCK) ? bcnt[2 * t + 1] : 0;
    s2[t] = a0 + a1;
    __syncthreads();
    for (int off = 1; off < 256; off <<= 1) {
        int x = (t >= off) ? s2[t - off] : 0;
        __syncthreads();
        s2[t] += x;
        __syncthreads();
    }
    int excl = s2[t] - a0 - a1;
    if (2 * t < NBUCK)     { bbase[2 * t] = excl;          bcur[2 * t] = excl; }
    if (2 * t + 1 < NBUCK) { bbase[2 * t + 1] = excl + a0; bcur[2 * t + 1] = excl + a0; }
    if (t == 255) { bbase[NBUCK] = s2[255]; offsets[NN] = s2[255]; }  // = EE
}

// ---------------- Pass A: bin edges into bucket-grouped tmp (packed (src<<8)|dstlow) ----
__global__ __launch_bounds__(256) void binA_kernel(const int* __restrict__ src,
                                                   const int* __restrict__ dst,
                                                   int* __restrict__ bcur,
                                                   unsigned* __restrict__ tmp) {
    __shared__ int hist[NBUCK];
    __shared__ int scn[NBUCK + 1];
    __shared__ int cur[NBUCK];
    __shared__ int gbase[NBUCK];
    __shared__ int s2[256];
    __shared__ unsigned staged[CHUNK];
    int t = threadIdx.x;
    for (int i = t; i < NBUCK; i += 256) hist[i] = 0;
    __syncthreads();
    int e0 = blockIdx.x * CHUNK;
    int nE = min(CHUNK, EE - e0);

    int my_e[16], my_bk[16];
#pragma unroll
    for (int k = 0; k < 16; k++) {
        int li = t + k * 256;
        bool ok = li < nE;
        int idx = ok ? (e0 + li) : e0;
        int d = dst[idx];
        int s = src[idx];
        int b = d >> BSH;
        my_e[k] = (s << 8) | (d & 255);
        my_bk[k] = ok ? b : -1;
        if (ok) atomicAdd(&hist[b], 1);
    }
    __syncthreads();
    int a0 = (2 * t < NBUCK) ? hist[2 * t] : 0;
    int a1 = (2 * t + 1 < NBUCK) ? hist[2 * t + 1] : 0;
    s2[t] = a0 + a1;
    __syncthreads();
    for (int off = 1; off < 256; off <<= 1) {
        int x = (t >= off) ? s2[t - off] : 0;
        __syncthreads();
        s2[t] += x;
        __syncthreads();
    }
    int excl = s2[t] - a0 - a1;
    if (2 * t < NBUCK)     { scn[2 * t] = excl;          cur[2 * t] = excl; }
    if (2 * t + 1 < NBUCK) { scn[2 * t + 1] = excl + a0; cur[2 * t + 1] = excl + a0; }
    if (t == 0) scn[NBUCK] = nE;
    __syncthreads();
    for (int i = t; i < NBUCK; i += 256)
        gbase[i] = hist[i] ? atomicAdd(&bcur[i], hist[i]) : 0;
    __syncthreads();
#pragma unroll
    for (int k = 0; k < 16; k++) {
        if (my_bk[k] >= 0) {
            int lp = atomicAdd(&cur[my_bk[k]], 1);
            staged[lp] = (unsigned)my_e[k];
        }
    }
    __syncthreads();
    for (int i = t; i < nE; i += 256) {
        int lo = 0, hi = NBUCK;
#pragma unroll
        for (int step = 0; step < 9; step++) {
            int mid = (lo + hi) >> 1;
            bool c = scn[mid] <= i;
            lo = c ? mid : lo;
            hi = c ? hi : mid;
        }
        tmp[gbase[lo] + (i - scn[lo])] = staged[i];
    }
}

// ---------------- Pass B: per-bucket node histogram + scan -> offsets/dinv/csr ----------
__global__ __launch_bounds__(256) void binB_kernel(const unsigned* __restrict__ tmp,
                                                   const int* __restrict__ bbase,
                                                   int* __restrict__ csr,
                                                   int* __restrict__ offsets,
                                                   float* __restrict__ dinv) {
    __shared__ int hist[BNODES], cur[BNODES], sc[BNODES];
    int b = blockIdx.x, t = threadIdx.x;
    int e0 = bbase[b], e1 = bbase[b + 1];
    hist[t] = 0;
    __syncthreads();
    for (int i = e0 + t; i < e1; i += 256) atomicAdd(&hist[tmp[i] & 255], 1);
    __syncthreads();
    int v = hist[t];
    sc[t] = v;
    __syncthreads();
    for (int off = 1; off < 256; off <<= 1) {
        int x = (t >= off) ? sc[t - off] : 0;
        __syncthreads();
        sc[t] += x;
        __syncthreads();
    }
    int excl = sc[t] - v;
    cur[t] = e0 + excl;
    int node = (b << BSH) + t;
    if (node < NN) {
        offsets[node] = e0 + excl;
        dinv[node] = 1.0f / sqrtf((float)v + 1.0f);
    }
    __syncthreads();
    for (int i = e0 + t; i < e1; i += 256) {
        unsigned u = tmp[i];
        int pos = atomicAdd(&cur[u & 255], 1);
        csr[pos] = (int)(u >> 8);
    }
}

// ---------------- GEMM + dinv-scale epilogue: Y[r,:] = (X[r,:]@W) * dinv[r] ----------
// 256 threads; each thread computes 4 rows x 4 cols. X tile padded (+4 floats) in LDS.
template <int K, int NC>
__global__ __launch_bounds__(256) void gemm_kernel(const float* __restrict__ X,
                                                   const float* __restrict__ W,
                                                   const float* __restrict__ dinv,
                                                   float* __restrict__ Y) {
    constexpr int CG   = NC / 4;        // col groups of 4
    constexpr int RS   = 256 / CG;      // row-slots
    constexpr int ROWS = RS * 4;        // rows per block
    constexpr int XP   = K + 4;         // padded X leading dim (bank-conflict-free)
    __shared__ float Wl[K * NC];
    __shared__ float Xl[ROWS * XP];
    const int t = threadIdx.x;
    const int row0 = blockIdx.x * ROWS;

    for (int i = t; i < K * (NC / 4); i += 256) {
        int k = i / (NC / 4), c = i % (NC / 4);
        *(float4*)&Wl[k * NC + c * 4] = *(const float4*)&W[k * NC + c * 4];
    }
    for (int i = t; i < ROWS * (K / 4); i += 256) {
        int r = i / (K / 4), c = i % (K / 4);
        float4 v = make_float4(0.f, 0.f, 0.f, 0.f);
        if (row0 + r < NN) v = *(const float4*)&X[(row0 + r) * K + c * 4];
        *(float4*)&Xl[r * XP + c * 4] = v;
    }
    __syncthreads();

    const int cg = t & (CG - 1);
    const int rs = t / CG;
    float4 acc[4];
#pragma unroll
    for (int rr = 0; rr < 4; rr++) acc[rr] = make_float4(0.f, 0.f, 0.f, 0.f);

#pragma unroll 4
    for (int k = 0; k < K; k += 4) {
        float4 w0 = *(const float4*)&Wl[(k + 0) * NC + cg * 4];
        float4 w1 = *(const float4*)&Wl[(k + 1) * NC + cg * 4];
        float4 w2 = *(const float4*)&Wl[(k + 2) * NC + cg * 4];
        float4 w3 = *(const float4*)&Wl[(k + 3) * NC + cg * 4];
#pragma unroll
        for (int rr = 0; rr < 4; rr++) {
            float4 xv = *(const float4*)&Xl[(rs * 4 + rr) * XP + k];
            acc[rr].x += xv.x * w0.x + xv.y * w1.x + xv.z * w2.x + xv.w * w3.x;
            acc[rr].y += xv.x * w0.y + xv.y * w1.y + xv.z * w2.y + xv.w * w3.y;
            acc[rr].z += xv.x * w0.z + xv.y * w1.z + xv.z * w2.z + xv.w * w3.z;
            acc[rr].w += xv.x * w0.w + xv.y * w1.w + xv.z * w2.w + xv.w * w3.w;
        }
    }
#pragma unroll
    for (int rr = 0; rr < 4; rr++) {
        int row = row0 + rs * 4 + rr;
        if (row < NN) {
            float s = dinv[row];
            float4 r = acc[rr];
            r.x *= s; r.y *= s; r.z *= s; r.w *= s;
            *(float4*)&Y[row * NC + cg * 4] = r;
        }
    }
}

// ---------------- gather layer 1 (F=64): wave/node, 4 edge-slots x 16 fgroups -------
// Hs rows are pre-scaled by dinv[src]; out = relu(dv*(Hs[node] + sum Hs[s]) + b)
__global__ __launch_bounds__(256) void gather1_kernel(const int* __restrict__ offsets,
                                                      const int* __restrict__ csr,
                                                      const float* __restrict__ dinv,
                                                      const float* __restrict__ Hs,
                                                      const float* __restrict__ b,
                                                      float* __restrict__ out) {
    int node = (blockIdx.x * 256 + threadIdx.x) >> 6;
    int lane = threadIdx.x & 63;
    if (node >= NN) return;
    int fg = lane & 15, es = lane >> 4;
    int start = offsets[node], end = offsets[node + 1];
    float4 acc = make_float4(0.f, 0.f, 0.f, 0.f);
    for (int k = start + es; k < end; k += 4) {
        int s = csr[k];
        float4 h = *(const float4*)&Hs[s * DH + fg * 4];
        acc.x += h.x; acc.y += h.y; acc.z += h.z; acc.w += h.w;
    }
    acc.x += __shfl_xor(acc.x, 16); acc.y += __shfl_xor(acc.y, 16);
    acc.z += __shfl_xor(acc.z, 16); acc.w += __shfl_xor(acc.w, 16);
    acc.x += __shfl_xor(acc.x, 32); acc.y += __shfl_xor(acc.y, 32);
    acc.z += __shfl_xor(acc.z, 32); acc.w += __shfl_xor(acc.w, 32);
    float dv = dinv[node];
    float4 self = *(const float4*)&Hs[node * DH + fg * 4];
    float4 b4 = *(const float4*)&b[fg * 4];
    float4 v;
    v.x = fmaxf(dv * (acc.x + self.x) + b4.x, 0.f);
    v.y = fmaxf(dv * (acc.y + self.y) + b4.y, 0.f);
    v.z = fmaxf(dv * (acc.z + self.z) + b4.z, 0.f);
    v.w = fmaxf(dv * (acc.w + self.w) + b4.w, 0.f);
    if (lane < 16) *(float4*)&out[node * DH + fg * 4] = v;
}

// ---------------- gather layer 2 (F=32): wave/node, 8 edge-slots x 8 fgroups + fc ----
__global__ __launch_bounds__(256) void gather2_kernel(const int* __restrict__ offsets,
                                                      const int* __restrict__ csr,
                                                      const float* __restrict__ dinv,
                                                      const float* __restrict__ Hs,
                                                      const float* __restrict__ b,
                                                      const float* __restrict__ fcw,
                                                      const float* __restrict__ fcb,
                                                      float* __restrict__ h2,
                                                      float* __restrict__ scores) {
    int node = (blockIdx.x * 256 + threadIdx.x) >> 6;
    int lane = threadIdx.x & 63;
    if (node >= NN) return;
    int fg = lane & 7, es = lane >> 3;
    int start = offsets[node], end = offsets[node + 1];
    float4 acc = make_float4(0.f, 0.f, 0.f, 0.f);
    for (int k = start + es; k < end; k += 8) {
        int s = csr[k];
        float4 h = *(const float4*)&Hs[s * DOUT + fg * 4];
        acc.x += h.x; acc.y += h.y; acc.z += h.z; acc.w += h.w;
    }
#pragma unroll
    for (int m = 8; m <= 32; m <<= 1) {
        acc.x += __shfl_xor(acc.x, m); acc.y += __shfl_xor(acc.y, m);
        acc.z += __shfl_xor(acc.z, m); acc.w += __shfl_xor(acc.w, m);
    }
    float dv = dinv[node];
    float4 self = *(const float4*)&Hs[node * DOUT + fg * 4];
    float4 b4 = *(const float4*)&b[fg * 4];
    float4 v;
    v.x = fmaxf(dv * (acc.x + self.x) + b4.x, 0.f);
    v.y = fmaxf(dv * (acc.y + self.y) + b4.y, 0.f);
    v.z = fmaxf(dv * (acc.z + self.z) + b4.z, 0.f);
    v.w = fmaxf(dv * (acc.w + self.w) + b4.w, 0.f);
    if (lane < 8) *(float4*)&h2[node * DOUT + fg * 4] = v;
    float4 fw = *(const float4*)&fcw[fg * 4];
    float sv = v.x * fw.x + v.y * fw.y + v.z * fw.z + v.w * fw.w;
    sv += __shfl_xor(sv, 1); sv += __shfl_xor(sv, 2); sv += __shfl_xor(sv, 4);
    if (lane == 0) scores[node] = sv + fcb[0];
}

extern "C" void kernel_launch(void* const* d_in, const int* in_sizes, int n_in,
                              void* d_out, int out_size, void* d_ws, size_t ws_size,
                              hipStream_t stream) {
    const float* x   = (const float*)d_in[0];
    const int*   ei  = (const int*)d_in[1];
    const float* W1  = (const float*)d_in[2];
    const float* b1  = (const float*)d_in[3];
    const float* W2  = (const float*)d_in[4];
    const float* b2  = (const float*)d_in[5];
    const float* fcw = (const float*)d_in[6];
    const float* fcb = (const float*)d_in[7];
    const int* src = ei;
    const int* dst = ei + EE;

    float* ws = (float*)d_ws;
    float* dinv    = ws;                          // NN
    int*   offsets = (int*)(ws + NN);             // NN+1
    int*   bcnt    = (int*)(ws + 2 * NN + 64);    // NBUCK
    int*   bbase   = bcnt + 512;                  // NBUCK+1
    int*   bcur    = bbase + 512;                 // NBUCK
    int*   csr     = bcur + 512;                  // EE
    float* bigreg  = (float*)(csr + EE);          // max(EE, NN*64): tmp then Hs1
    unsigned* tmp  = (unsigned*)bigreg;           // EE (dead after binB)
    float* Hs1     = bigreg;                      // NN*64 (after binB)
    float* h1      = bigreg + NN * DH;            // NN*64
    float* Hs2     = h1 + NN * DH;                // NN*32

    float* out    = (float*)d_out;
    float* scores = out;          // NN
    float* h2     = out + NN;     // NN*32

    const int T = 256;
    // CSR build (two-pass binning)
    zero_bcnt_kernel<<<2, 256, 0, stream>>>(bcnt);
    bhist_kernel<<<NCHUNK, T, 0, stream>>>(dst, bcnt);
    bscan_kernel<<<1, T, 0, stream>>>(bcnt, bbase, bcur, offsets);
    binA_kernel<<<NCHUNK, T, 0, stream>>>(src, dst, bcur, tmp);
    binB_kernel<<<NBUCK, T, 0, stream>>>(tmp, bbase, csr, offsets, dinv);
    // layer 1: Hs1 = (x@W1)*dinv  (64 rows/block)
    gemm_kernel<DIN, DH><<<(NN + 63) / 64, T, 0, stream>>>(x, W1, dinv, Hs1);
    gather1_kernel<<<(NN * 64 + T - 1) / T, T, 0, stream>>>(offsets, csr, dinv, Hs1, b1, h1);
    // layer 2: Hs2 = (h1@W2)*dinv  (128 rows/block)
    gemm_kernel<DH, DOUT><<<(NN + 127) / 128, T, 0, stream>>>(h1, W2, dinv, Hs2);
    gather2_kernel<<<(NN * 64 + T - 1) / T, T, 0, stream>>>(offsets, csr, dinv, Hs2, b2, fcw, fcb, h2, scores);
}